// Round 1
// baseline (637.279 us; speedup 1.0000x reference)
//
#include <hip/hip_runtime.h>
#include <hip/hip_bf16.h>

#define VOCAB 128
#define EMB   10
#define HID   20
#define BATCH 256
#define TLEN  2048
// tanh(x) = 1 - 2/(exp(2x)+1); v_exp_f32 computes 2^z, so fold 2*log2(e)
// into W_hh and the P table:  z = PRESCALE * (xw + W_hh h)
#define PRESCALE 2.8853900817779268f

// ---------------------------------------------------------------------------
// Kernel A: P[v][j] = PRESCALE * (b_ih[j] + b_hh[j] + sum_e W_ih[j,e]*emb[v,e])
// ---------------------------------------------------------------------------
__global__ __launch_bounds__(256)
void build_table(const float* __restrict__ emb, const float* __restrict__ W_ih,
                 const float* __restrict__ b_ih, const float* __restrict__ b_hh,
                 float* __restrict__ P) {
    int idx = blockIdx.x * blockDim.x + threadIdx.x;
    if (idx < VOCAB * HID) {
        int v = idx / HID, j = idx % HID;
        float acc = b_ih[j] + b_hh[j];
        #pragma unroll
        for (int e = 0; e < EMB; ++e)
            acc = fmaf(W_ih[j * EMB + e], emb[v * EMB + e], acc);
        P[idx] = acc * PRESCALE;
    }
}

// ---------------------------------------------------------------------------
// Kernel B: the sequential recurrence. One wave per batch row (latency-bound).
// Lane j holds h_j and W_hh row j (pre-scaled). Broadcast via v_readlane.
// ---------------------------------------------------------------------------
__global__ __launch_bounds__(64)
void rnn_scan(const int* __restrict__ tokens, const float* __restrict__ W_hh,
              const float* __restrict__ P, float* __restrict__ hs) {
    __shared__ float Pl[VOCAB * HID];   // 10240 B
    __shared__ int   tok[TLEN];         //  8192 B
    const int lane = threadIdx.x;
    const int b    = blockIdx.x;

    for (int i = lane; i < VOCAB * HID; i += 64) Pl[i] = P[i];
    const int4* src = (const int4*)(tokens + (size_t)b * TLEN);
    int4* dst = (int4*)tok;
    for (int i = lane; i < TLEN / 4; i += 64) dst[i] = src[i];

    const int j = lane < HID ? lane : HID - 1;   // lanes >= 20 do harmless dup work
    float w[HID];
    #pragma unroll
    for (int k = 0; k < HID; ++k) w[k] = W_hh[j * HID + k] * PRESCALE;
    __syncthreads();

    float h = 0.0f;
    float* out = hs + (size_t)b * TLEN * HID;
    #pragma unroll 2
    for (int t = 0; t < TLEN; ++t) {
        const int tk = tok[t];                 // uniform LDS broadcast, off-chain
        float a0 = Pl[tk * HID + j];           // xw lookup, off-chain (prefetchable)
        float a1 = 0.f, a2 = 0.f, a3 = 0.f;
        #pragma unroll
        for (int k = 0; k < HID; k += 4) {
            const float h0 = __int_as_float(__builtin_amdgcn_readlane(__float_as_int(h), k + 0));
            const float h1 = __int_as_float(__builtin_amdgcn_readlane(__float_as_int(h), k + 1));
            const float h2 = __int_as_float(__builtin_amdgcn_readlane(__float_as_int(h), k + 2));
            const float h3 = __int_as_float(__builtin_amdgcn_readlane(__float_as_int(h), k + 3));
            a0 = fmaf(w[k + 0], h0, a0);
            a1 = fmaf(w[k + 1], h1, a1);
            a2 = fmaf(w[k + 2], h2, a2);
            a3 = fmaf(w[k + 3], h3, a3);
        }
        const float z = (a0 + a1) + (a2 + a3);         // = 2*log2e*(xw + W h)
        const float u = __builtin_amdgcn_exp2f(z);     // e^{2x}
        const float r = __builtin_amdgcn_rcpf(u + 1.0f);
        h = fmaf(-2.0f, r, 1.0f);                      // tanh(x)
        if (lane < HID) out[(size_t)t * HID + lane] = h;
    }
}

// ---------------------------------------------------------------------------
// Kernel C: out[p, v] = b_out[v] + sum_j hs[p, j] * W_out[v, j]
// Block tile: 64 positions x 128 vocab; thread tile 4p x 8v (two 4v halves).
// ---------------------------------------------------------------------------
__global__ __launch_bounds__(256)
void proj_kernel(const float* __restrict__ hs, const float* __restrict__ W_out,
                 const float* __restrict__ b_out, float* __restrict__ out) {
    __shared__ float ht[HID * 64];      // transposed: ht[j][p]
    __shared__ float Wt[HID * VOCAB];   // transposed: Wt[j][v]
    __shared__ float bo[VOCAB];
    const int tid = threadIdx.x;
    const long P0 = (long)blockIdx.x * 64;

    // stage h tile (coalesced float4 load, scattered LDS transpose write)
    const float4* hs4 = (const float4*)(hs + P0 * HID);
    for (int i = tid; i < 64 * HID / 4; i += 256) {
        float4 v = hs4[i];
        int idx = i * 4;
        ht[((idx + 0) % HID) * 64 + (idx + 0) / HID] = v.x;
        ht[((idx + 1) % HID) * 64 + (idx + 1) / HID] = v.y;
        ht[((idx + 2) % HID) * 64 + (idx + 2) / HID] = v.z;
        ht[((idx + 3) % HID) * 64 + (idx + 3) / HID] = v.w;
    }
    // stage W_out transposed (tiny, L2-hot)
    for (int i = tid; i < HID * VOCAB; i += 256) {
        int j = i >> 7, v = i & 127;
        Wt[i] = W_out[v * HID + j];
    }
    if (tid < VOCAB) bo[tid] = b_out[tid];
    __syncthreads();

    const int vg = tid & 15, pg = tid >> 4;  // 16 v-groups x 16 p-groups
    const int p0 = pg * 4;
    const int va = vg * 4, vb = 64 + vg * 4;

    float acc[4][8];
    #pragma unroll
    for (int p = 0; p < 4; ++p)
        #pragma unroll
        for (int c = 0; c < 4; ++c) {
            acc[p][c]     = bo[va + c];
            acc[p][4 + c] = bo[vb + c];
        }
    #pragma unroll
    for (int jj = 0; jj < HID; ++jj) {
        float4 hv = *(const float4*)&ht[jj * 64 + p0];
        float4 wa = *(const float4*)&Wt[jj * VOCAB + va];
        float4 wb = *(const float4*)&Wt[jj * VOCAB + vb];
        const float hh[4]  = {hv.x, hv.y, hv.z, hv.w};
        const float wwa[4] = {wa.x, wa.y, wa.z, wa.w};
        const float wwb[4] = {wb.x, wb.y, wb.z, wb.w};
        #pragma unroll
        for (int p = 0; p < 4; ++p)
            #pragma unroll
            for (int c = 0; c < 4; ++c) {
                acc[p][c]     = fmaf(hh[p], wwa[c], acc[p][c]);
                acc[p][4 + c] = fmaf(hh[p], wwb[c], acc[p][4 + c]);
            }
    }
    #pragma unroll
    for (int p = 0; p < 4; ++p) {
        float4 oa = {acc[p][0], acc[p][1], acc[p][2], acc[p][3]};
        float4 ob = {acc[p][4], acc[p][5], acc[p][6], acc[p][7]};
        float* dstp = out + (P0 + p0 + p) * (long)VOCAB;
        *(float4*)(dstp + va) = oa;
        *(float4*)(dstp + vb) = ob;
    }
}

extern "C" void kernel_launch(void* const* d_in, const int* in_sizes, int n_in,
                              void* d_out, int out_size, void* d_ws, size_t ws_size,
                              hipStream_t stream) {
    const int*   inputs = (const int*)  d_in[0];
    const float* emb    = (const float*)d_in[1];
    const float* W_ih   = (const float*)d_in[2];
    const float* W_hh   = (const float*)d_in[3];
    const float* b_ih   = (const float*)d_in[4];
    const float* b_hh   = (const float*)d_in[5];
    const float* W_out  = (const float*)d_in[6];
    const float* b_out  = (const float*)d_in[7];
    float* out = (float*)d_out;

    float* P  = (float*)d_ws;                      // 10240 B (rounded to 16 KiB)
    float* hs = (float*)((char*)d_ws + 16384);     // BATCH*TLEN*HID fp32 = 41.9 MB

    build_table<<<(VOCAB * HID + 255) / 256, 256, 0, stream>>>(emb, W_ih, b_ih, b_hh, P);
    rnn_scan<<<BATCH, 64, 0, stream>>>(inputs, W_hh, P, hs);
    proj_kernel<<<(BATCH * TLEN) / 64, 256, 0, stream>>>(hs, W_out, b_out, out);
}

// Round 2
// 576.168 us; speedup vs baseline: 1.1061x; 1.1061x over previous
//
#include <hip/hip_runtime.h>
#include <hip/hip_bf16.h>

#define VOCAB 128
#define EMB   10
#define HID   20
#define BATCH 256
#define TLEN  2048
// tanh(x) = 1 - 2/(exp(2x)+1); v_exp_f32 computes 2^z, so fold 2*log2(e)
// into W_hh and the P table:  z = PRESCALE * (xw + W_hh h)
#define PRESCALE 2.8853900817779268f

// ---------------------------------------------------------------------------
// Kernel A: P[v][j] = PRESCALE * (b_ih[j] + b_hh[j] + sum_e W_ih[j,e]*emb[v,e])
// ---------------------------------------------------------------------------
__global__ __launch_bounds__(256)
void build_table(const float* __restrict__ emb, const float* __restrict__ W_ih,
                 const float* __restrict__ b_ih, const float* __restrict__ b_hh,
                 float* __restrict__ P) {
    int idx = blockIdx.x * blockDim.x + threadIdx.x;
    if (idx < VOCAB * HID) {
        int v = idx / HID, j = idx % HID;
        float acc = b_ih[j] + b_hh[j];
        #pragma unroll
        for (int e = 0; e < EMB; ++e)
            acc = fmaf(W_ih[j * EMB + e], emb[v * EMB + e], acc);
        P[idx] = acc * PRESCALE;
    }
}

// ---------------------------------------------------------------------------
// Kernel B: sequential recurrence, 1 wave per batch row (latency-bound).
// Lane j holds h_j and W_hh row j. All LDS lookups (tok, Pl) are software-
// pipelined 8-16 steps ahead so the per-step chain is pure VALU.
// hs is written bf16 in [B][HID][T] layout: lane j owns a contiguous t-row,
// packing 2 steps per 4-byte store.
// ---------------------------------------------------------------------------
#define RNN_STEP(XW) { \
    float a0 = (XW), a1 = 0.f, a2 = 0.f, a3 = 0.f; \
    _Pragma("unroll") \
    for (int k = 0; k < HID; k += 4) { \
        float h0 = __int_as_float(__builtin_amdgcn_readlane(__float_as_int(h), k + 0)); \
        float h1 = __int_as_float(__builtin_amdgcn_readlane(__float_as_int(h), k + 1)); \
        float h2 = __int_as_float(__builtin_amdgcn_readlane(__float_as_int(h), k + 2)); \
        float h3 = __int_as_float(__builtin_amdgcn_readlane(__float_as_int(h), k + 3)); \
        a0 = fmaf(w[k + 0], h0, a0); a1 = fmaf(w[k + 1], h1, a1); \
        a2 = fmaf(w[k + 2], h2, a2); a3 = fmaf(w[k + 3], h3, a3); } \
    float z_ = (a0 + a1) + (a2 + a3); \
    float u_ = __builtin_amdgcn_exp2f(z_); \
    float r_ = __builtin_amdgcn_rcpf(u_ + 1.0f); \
    h = fmaf(-2.0f, r_, 1.0f); }

__device__ __forceinline__ unsigned f2bf(float f) {
    unsigned u = __float_as_uint(f);
    return (u + 0x7FFFu + ((u >> 16) & 1u)) >> 16;   // RNE truncate
}

__global__ __launch_bounds__(64)
void rnn_scan(const int* __restrict__ tokens, const float* __restrict__ W_hh,
              const float* __restrict__ P, __hip_bfloat16* __restrict__ hs) {
    __shared__ float Pl[VOCAB * HID];     // 10240 B
    __shared__ int   tok[TLEN + 16];      //  8256 B (pad for prefetch overrun)
    const int lane = threadIdx.x;
    const int b    = blockIdx.x;

    for (int i = lane; i < VOCAB * HID; i += 64) Pl[i] = P[i];
    const int4* src = (const int4*)(tokens + (size_t)b * TLEN);
    int4* dst = (int4*)tok;
    for (int i = lane; i < TLEN / 4; i += 64) dst[i] = src[i];
    if (lane < 16) tok[TLEN + lane] = 0;

    const int j = lane < HID ? lane : HID - 1;   // lanes >= 20: harmless dup work
    float w[HID];
    #pragma unroll
    for (int k = 0; k < HID; ++k) w[k] = W_hh[j * HID + k] * PRESCALE;
    __syncthreads();

    float h = 0.0f;
    __hip_bfloat16* outp = hs + ((size_t)b * HID + j) * TLEN;  // lane j's t-row

    // pipeline prologue: tokens for steps 0..15, xw for steps 0..7
    int4 ta  = *(const int4*)&tok[0];
    int4 tb  = *(const int4*)&tok[4];
    int4 tkc = *(const int4*)&tok[8];
    int4 tkd = *(const int4*)&tok[12];
    float xw0[4] = {Pl[ta.x * HID + j], Pl[ta.y * HID + j],
                    Pl[ta.z * HID + j], Pl[ta.w * HID + j]};
    float xw1[4] = {Pl[tb.x * HID + j], Pl[tb.y * HID + j],
                    Pl[tb.z * HID + j], Pl[tb.w * HID + j]};

    for (int t = 0; t < TLEN; t += 8) {
        float hA;
        // ---- group 0: steps t..t+3 ----
        RNN_STEP(xw0[0]); hA = h;
        RNN_STEP(xw0[1]);
        if (lane < HID) *(unsigned*)(outp + t) = f2bf(hA) | (f2bf(h) << 16);
        RNN_STEP(xw0[2]); hA = h;
        RNN_STEP(xw0[3]);
        if (lane < HID) *(unsigned*)(outp + t + 2) = f2bf(hA) | (f2bf(h) << 16);
        // refill xw0 for steps t+8..t+11 (latency hidden by group 1)
        float n0[4] = {Pl[tkc.x * HID + j], Pl[tkc.y * HID + j],
                       Pl[tkc.z * HID + j], Pl[tkc.w * HID + j]};
        tkc = *(const int4*)&tok[t + 16];
        // ---- group 1: steps t+4..t+7 ----
        RNN_STEP(xw1[0]); hA = h;
        RNN_STEP(xw1[1]);
        if (lane < HID) *(unsigned*)(outp + t + 4) = f2bf(hA) | (f2bf(h) << 16);
        RNN_STEP(xw1[2]); hA = h;
        RNN_STEP(xw1[3]);
        if (lane < HID) *(unsigned*)(outp + t + 6) = f2bf(hA) | (f2bf(h) << 16);
        // refill xw1 for steps t+12..t+15
        float n1[4] = {Pl[tkd.x * HID + j], Pl[tkd.y * HID + j],
                       Pl[tkd.z * HID + j], Pl[tkd.w * HID + j]};
        tkd = *(const int4*)&tok[t + 20];
        #pragma unroll
        for (int u = 0; u < 4; ++u) { xw0[u] = n0[u]; xw1[u] = n1[u]; }
    }
}

// ---------------------------------------------------------------------------
// Kernel C: out[p, v] = b_out[v] + sum_j hs_bf16[b][j][t] * W_out[v, j]
// Block: one (b, 64-step chunk). hs arrives pre-transposed -> no LDS scatter.
// Thread tile 4p x 8v.
// ---------------------------------------------------------------------------
__global__ __launch_bounds__(256)
void proj_kernel(const __hip_bfloat16* __restrict__ hs, const float* __restrict__ W_out,
                 const float* __restrict__ b_out, float* __restrict__ out) {
    __shared__ float ht[HID * 64];      //  5120 B  ht[j][t']
    __shared__ float Wt[HID * VOCAB];   // 10240 B  Wt[j][v]
    __shared__ float bo[VOCAB];
    const int tid = threadIdx.x;
    const int blk = blockIdx.x;
    const int b   = blk >> 5;
    const int t0  = (blk & 31) * 64;

    // stage h tile: 20 rows x 64 bf16 (coalesced ushort4, convert to fp32)
    const __hip_bfloat16* hb = hs + (size_t)b * HID * TLEN + t0;
    for (int i = tid; i < HID * 16; i += 256) {
        int jj = i >> 4, q = i & 15;
        ushort4 v = *(const ushort4*)(hb + jj * TLEN + q * 4);
        float* d = &ht[jj * 64 + q * 4];
        d[0] = __uint_as_float((unsigned)v.x << 16);
        d[1] = __uint_as_float((unsigned)v.y << 16);
        d[2] = __uint_as_float((unsigned)v.z << 16);
        d[3] = __uint_as_float((unsigned)v.w << 16);
    }
    for (int i = tid; i < HID * VOCAB; i += 256) {
        int jj = i >> 7, v = i & 127;
        Wt[i] = W_out[v * HID + jj];
    }
    if (tid < VOCAB) bo[tid] = b_out[tid];
    __syncthreads();

    const int vg = tid & 15, pg = tid >> 4;
    const int p0 = pg * 4;
    const int va = vg * 4, vb = 64 + vg * 4;

    float acc[4][8];
    #pragma unroll
    for (int p = 0; p < 4; ++p)
        #pragma unroll
        for (int c = 0; c < 4; ++c) {
            acc[p][c]     = bo[va + c];
            acc[p][4 + c] = bo[vb + c];
        }
    #pragma unroll
    for (int jj = 0; jj < HID; ++jj) {
        float4 hv = *(const float4*)&ht[jj * 64 + p0];
        float4 wa = *(const float4*)&Wt[jj * VOCAB + va];
        float4 wb = *(const float4*)&Wt[jj * VOCAB + vb];
        const float hh[4]  = {hv.x, hv.y, hv.z, hv.w};
        const float wwa[4] = {wa.x, wa.y, wa.z, wa.w};
        const float wwb[4] = {wb.x, wb.y, wb.z, wb.w};
        #pragma unroll
        for (int p = 0; p < 4; ++p)
            #pragma unroll
            for (int c = 0; c < 4; ++c) {
                acc[p][c]     = fmaf(hh[p], wwa[c], acc[p][c]);
                acc[p][4 + c] = fmaf(hh[p], wwb[c], acc[p][4 + c]);
            }
    }
    #pragma unroll
    for (int p = 0; p < 4; ++p) {
        float4 oa = {acc[p][0], acc[p][1], acc[p][2], acc[p][3]};
        float4 ob = {acc[p][4], acc[p][5], acc[p][6], acc[p][7]};
        float* dstp = out + ((size_t)b * TLEN + t0 + p0 + p) * VOCAB;
        *(float4*)(dstp + va) = oa;
        *(float4*)(dstp + vb) = ob;
    }
}

extern "C" void kernel_launch(void* const* d_in, const int* in_sizes, int n_in,
                              void* d_out, int out_size, void* d_ws, size_t ws_size,
                              hipStream_t stream) {
    const int*   inputs = (const int*)  d_in[0];
    const float* emb    = (const float*)d_in[1];
    const float* W_ih   = (const float*)d_in[2];
    const float* W_hh   = (const float*)d_in[3];
    const float* b_ih   = (const float*)d_in[4];
    const float* b_hh   = (const float*)d_in[5];
    const float* W_out  = (const float*)d_in[6];
    const float* b_out  = (const float*)d_in[7];
    float* out = (float*)d_out;

    float* P = (float*)d_ws;                                   // 10240 B
    __hip_bfloat16* hs = (__hip_bfloat16*)((char*)d_ws + 16384); // 21 MB bf16 [B][HID][T]

    build_table<<<(VOCAB * HID + 255) / 256, 256, 0, stream>>>(emb, W_ih, b_ih, b_hh, P);
    rnn_scan<<<BATCH, 64, 0, stream>>>(inputs, W_hh, P, hs);
    proj_kernel<<<BATCH * (TLEN / 64), 256, 0, stream>>>(hs, W_out, b_out, out);
}